// Round 9
// baseline (1135.957 us; speedup 1.0000x reference)
//
#include <hip/hip_runtime.h>

#define DD 64
#define LL 5
#define GG 512
#define AFN 9
#define AVN 120
#define BFN 3
#define BVN 6
#define BNEPS 1e-5f
#define SCB 1024
#define NSLAB 4          // channel slabs for L2-resident gather
#define SCH 16           // channels per slab

typedef unsigned int uint;
typedef unsigned short ushort;
typedef short bhalf8 __attribute__((ext_vector_type(8)));
typedef float fx4 __attribute__((ext_vector_type(4)));

__device__ inline ushort f2bf(float f) {
  uint u = __float_as_uint(f);
  uint r = (u + 0x7FFF + ((u >> 16) & 1)) >> 16;   // round-to-nearest-even
  return (ushort)r;
}
__device__ inline float bf2f(ushort u) { return __uint_as_float(((uint)u) << 16); }

// h2 layout: 4 slabs of [N][16] bf16 — slab p holds channels [16p, 16p+16)

// ---------------- atom encoder ----------------
__global__ __launch_bounds__(256) void k_atom(
    const int* __restrict__ xf, const float* __restrict__ aemb,
    ushort* __restrict__ h2, int N)
{
  int t = blockIdx.x * 256 + threadIdx.x;
  int row = t >> 4, c4 = t & 15;
  if (row >= N) return;
  const int* x = xf + row * AFN;
  float4 s = make_float4(0.f, 0.f, 0.f, 0.f);
  #pragma unroll
  for (int f = 0; f < AFN; ++f) {
    int v = x[f];
    float4 w = ((const float4*)aemb)[(f * AVN + v) * 16 + c4];
    s.x += w.x; s.y += w.y; s.z += w.z; s.w += w.w;
  }
  ushort4 p;
  p.x = f2bf(s.x); p.y = f2bf(s.y); p.z = f2bf(s.z); p.w = f2bf(s.w);
  int slab = c4 >> 2;
  ushort* dst = h2 + (size_t)slab * N * SCH + (size_t)row * SCH + (c4 & 3) * 4;
  *(ushort4*)dst = p;
}

// ---------------- CSR build ----------------
__global__ __launch_bounds__(256) void k_hist(const int* __restrict__ ei,
    int* __restrict__ deg, int* __restrict__ rank, int E)
{
  int t = blockIdx.x * 256 + threadIdx.x;
  if (t >= E) return;
  rank[t] = atomicAdd(&deg[ei[E + t]], 1);
}

__global__ __launch_bounds__(1024) void k_scan1(const int* __restrict__ deg,
    int* __restrict__ scanned, int* __restrict__ bsum, int N)
{
  __shared__ int s[SCB];
  int i = blockIdx.x * SCB + threadIdx.x;
  int x = (i < N) ? deg[i] : 0;
  s[threadIdx.x] = x;
  for (int off = 1; off < SCB; off <<= 1) {
    __syncthreads();
    int v = (threadIdx.x >= off) ? s[threadIdx.x - off] : 0;
    __syncthreads();
    s[threadIdx.x] += v;
  }
  __syncthreads();
  if (i < N) scanned[i] = s[threadIdx.x] - x;
  if (threadIdx.x == SCB - 1) bsum[blockIdx.x] = s[SCB - 1];
}

__global__ __launch_bounds__(128) void k_scan2(const int* __restrict__ bsum,
    int* __restrict__ boff, int NB)
{
  __shared__ int s[128];
  int x = (threadIdx.x < NB) ? bsum[threadIdx.x] : 0;
  s[threadIdx.x] = x;
  for (int off = 1; off < 128; off <<= 1) {
    __syncthreads();
    int v = (threadIdx.x >= off) ? s[threadIdx.x - off] : 0;
    __syncthreads();
    s[threadIdx.x] += v;
  }
  __syncthreads();
  if (threadIdx.x < NB) boff[threadIdx.x] = s[threadIdx.x] - x;
}

__global__ __launch_bounds__(256) void k_fill(const int* __restrict__ ei,
    const int* __restrict__ ea, const int* __restrict__ scanned,
    const int* __restrict__ boff, const int* __restrict__ rank,
    int* __restrict__ rcarr, int E)
{
  int t = blockIdx.x * 256 + threadIdx.x;
  if (t >= E) return;
  int r = ei[t], c = ei[E + t];
  int code = ea[t * 3 + 0] + ea[t * 3 + 1] * 6 + ea[t * 3 + 2] * 36;
  int pos = scanned[c] + boff[c >> 10] + rank[t];
  rcarr[pos] = r | (code << 20);
}

__global__ __launch_bounds__(256) void k_bcomb(const float* __restrict__ bemb,
    float* __restrict__ bcomb)
{
  int t = blockIdx.x * 256 + threadIdx.x;
  if (t >= LL * 216 * DD) return;
  int ch = t & 63;
  int cl = t >> 6;
  int code = cl % 216;
  int l = cl / 216;
  int a0 = code % 6, a1 = (code / 6) % 6, a2 = code / 36;
  const float* B = bemb + (size_t)l * BFN * BVN * DD;
  bcomb[t] = B[(0 * BVN + a0) * DD + ch] + B[(1 * BVN + a1) * DD + ch]
           + B[(2 * BVN + a2) * DD + ch];
}

__global__ __launch_bounds__(256) void k_bounds(const int* __restrict__ batch,
    int* __restrict__ gs, int N)
{
  int g = blockIdx.x * 256 + threadIdx.x;
  if (g > GG) return;
  int lo = 0, hi = N;
  while (lo < hi) { int mid = (lo + hi) >> 1; if (batch[mid] < g) lo = mid + 1; else hi = mid; }
  gs[g] = lo;
}

// W fragments: [l][wsel][jt][kb][lane][r] -> bf16(W[kb*32+(lane>>4)*8+r][jt*16+(lane&15)])
__global__ __launch_bounds__(256) void k_wprep(const float* __restrict__ W1,
    const float* __restrict__ W2, ushort* __restrict__ wfrag)
{
  int t = blockIdx.x * 256 + threadIdx.x;
  if (t >= LL * 2 * 4096) return;
  int r = t & 7;
  int lane = (t >> 3) & 63;
  int kb = (t >> 9) & 1;
  int jt = (t >> 10) & 3;
  int wsel = (t >> 12) & 1;
  int l = t >> 13;
  int k = kb * 32 + ((lane >> 4) & 3) * 8 + r;
  int j = jt * 16 + (lane & 15);
  const float* Ws = (wsel ? W2 : W1) + (size_t)l * DD * DD;
  wfrag[t] = f2bf(Ws[k * DD + j]);
}

// ---------------- gather pass: one 16-channel slab, wave per node, 16 edges/iter ----------------
__global__ __launch_bounds__(256) void k_gather(
    const ushort* __restrict__ h2, const int* __restrict__ rcarr,
    const int* __restrict__ scanned, const int* __restrict__ boff,
    const float* __restrict__ bc, float* __restrict__ agg,
    int N, int E, int pass)
{
  int lane = threadIdx.x & 63;
  int node = blockIdx.x * 4 + (threadIdx.x >> 6);
  if (node >= N) return;
  int s = scanned[node] + boff[node >> 10];
  int e = (node + 1 < N) ? (scanned[node + 1] + boff[(node + 1) >> 10]) : E;
  int es = lane >> 2;        // edge slot 0..15
  int chq = lane & 3;        // channel quad within slab
  const ushort* slab = h2 + (size_t)pass * N * SCH;
  const float* bcs = bc + pass * SCH;
  float a0 = 0.f, a1 = 0.f, a2 = 0.f, a3 = 0.f;
  for (int k0 = s; k0 < e; k0 += 16) {
    int idx = k0 + es;
    bool valid = idx < e;
    int rck = rcarr[valid ? idx : s];
    int r = rck & 0xFFFFF;
    int code = (rck >> 20) & 0xFFF;
    uint2 hv = *(const uint2*)(slab + (size_t)r * SCH + chq * 4);
    float4 bv = *(const float4*)(bcs + code * DD + chq * 4);
    float f0 = __uint_as_float(hv.x << 16);
    float f1 = __uint_as_float(hv.x & 0xFFFF0000u);
    float f2 = __uint_as_float(hv.y << 16);
    float f3 = __uint_as_float(hv.y & 0xFFFF0000u);
    float m0 = fmaxf(f0 + bv.x, 0.f);
    float m1 = fmaxf(f1 + bv.y, 0.f);
    float m2 = fmaxf(f2 + bv.z, 0.f);
    float m3 = fmaxf(f3 + bv.w, 0.f);
    if (valid) { a0 += m0; a1 += m1; a2 += m2; a3 += m3; }
  }
  a0 += __shfl_xor(a0, 4);  a1 += __shfl_xor(a1, 4);
  a2 += __shfl_xor(a2, 4);  a3 += __shfl_xor(a3, 4);
  a0 += __shfl_xor(a0, 8);  a1 += __shfl_xor(a1, 8);
  a2 += __shfl_xor(a2, 8);  a3 += __shfl_xor(a3, 8);
  a0 += __shfl_xor(a0, 16); a1 += __shfl_xor(a1, 16);
  a2 += __shfl_xor(a2, 16); a3 += __shfl_xor(a3, 16);
  a0 += __shfl_xor(a0, 32); a1 += __shfl_xor(a1, 32);
  a2 += __shfl_xor(a2, 32); a3 += __shfl_xor(a3, 32);
  if (es == 0)
    *(float4*)(agg + (size_t)node * DD + pass * SCH + chq * 4) =
        make_float4(a0, a1, a2, a3);
}

// ---------------- mlpA (MFMA): z1 = ((1+eps)h + agg)@W1 + b1, bf16 out + stats ----------------
__global__ __launch_bounds__(256) void k_mlpA(
    const ushort* __restrict__ h2, const float* __restrict__ agg,
    const ushort* __restrict__ wfrag, const float* __restrict__ bvec,
    const float* __restrict__ epsl, ushort* __restrict__ z1b,
    float* __restrict__ stats, int N, int NT, int nwaves)
{
  __shared__ float sred[128];
  __shared__ ushort ldsT[4][16][72];
  if (threadIdx.x < 128) sred[threadIdx.x] = 0.f;
  __syncthreads();
  int lane = threadIdx.x & 63;
  int wid = threadIdx.x >> 6;
  int gwave = blockIdx.x * 4 + wid;
  int hi = lane >> 4, lo = lane & 15;
  float epsv = 1.f + epsl[0];
  bhalf8 af[8];
  #pragma unroll
  for (int f = 0; f < 8; ++f)
    af[f] = *(const bhalf8*)(wfrag + f * 512 + lane * 8);
  float4 bq[4];
  #pragma unroll
  for (int jt = 0; jt < 4; ++jt)
    bq[jt] = *(const float4*)(bvec + jt * 16 + hi * 4);
  float sS[4][4] = {{0}}, sQ[4][4] = {{0}};
  for (int mt = gwave; mt < NT; mt += nwaves) {
    int node = mt * 16 + lo;
    const float* arow = agg + (size_t)node * DD;
    bhalf8 bfr[2];
    #pragma unroll
    for (int kb = 0; kb < 2; ++kb) {
      int k0 = kb * 32 + hi * 8;
      // h channels k0..k0+7 live in slab k0>>4 at offset k0&15
      const ushort* hp = h2 + (size_t)(k0 >> 4) * N * SCH + (size_t)node * SCH + (k0 & 15);
      uint4 hv = *(const uint4*)hp;
      float4 aa = *(const float4*)(arow + k0);
      float4 ab = *(const float4*)(arow + k0 + 4);
      float xr[8];
      xr[0] = fmaf(epsv, __uint_as_float(hv.x << 16), aa.x);
      xr[1] = fmaf(epsv, __uint_as_float(hv.x & 0xFFFF0000u), aa.y);
      xr[2] = fmaf(epsv, __uint_as_float(hv.y << 16), aa.z);
      xr[3] = fmaf(epsv, __uint_as_float(hv.y & 0xFFFF0000u), aa.w);
      xr[4] = fmaf(epsv, __uint_as_float(hv.z << 16), ab.x);
      xr[5] = fmaf(epsv, __uint_as_float(hv.z & 0xFFFF0000u), ab.y);
      xr[6] = fmaf(epsv, __uint_as_float(hv.w << 16), ab.z);
      xr[7] = fmaf(epsv, __uint_as_float(hv.w & 0xFFFF0000u), ab.w);
      bhalf8 b8;
      #pragma unroll
      for (int r = 0; r < 8; ++r) b8[r] = (short)f2bf(xr[r]);
      bfr[kb] = b8;
    }
    fx4 acc[4];
    #pragma unroll
    for (int jt = 0; jt < 4; ++jt) {
      fx4 a = {0.f, 0.f, 0.f, 0.f};
      a = __builtin_amdgcn_mfma_f32_16x16x32_bf16(af[jt * 2 + 0], bfr[0], a, 0, 0, 0);
      a = __builtin_amdgcn_mfma_f32_16x16x32_bf16(af[jt * 2 + 1], bfr[1], a, 0, 0, 0);
      acc[jt] = a;
    }
    #pragma unroll
    for (int jt = 0; jt < 4; ++jt) {
      float z0 = acc[jt][0] + bq[jt].x;
      float z1 = acc[jt][1] + bq[jt].y;
      float z2 = acc[jt][2] + bq[jt].z;
      float z3 = acc[jt][3] + bq[jt].w;
      sS[jt][0] += z0; sQ[jt][0] += z0 * z0;
      sS[jt][1] += z1; sQ[jt][1] += z1 * z1;
      sS[jt][2] += z2; sQ[jt][2] += z2 * z2;
      sS[jt][3] += z3; sQ[jt][3] += z3 * z3;
      uint p0 = ((uint)f2bf(z1) << 16) | f2bf(z0);
      uint p1 = ((uint)f2bf(z3) << 16) | f2bf(z2);
      int jphys = jt ^ (lo & 3);
      *(uint2*)&ldsT[wid][lo][jphys * 16 + hi * 4] = make_uint2(p0, p1);
    }
    int row = lane >> 2, pch = lane & 3;
    int pphys = pch ^ (row & 3);
    const uint4* src = (const uint4*)&ldsT[wid][row][pphys * 16];
    uint4 v0 = src[0], v1 = src[1];
    uint4* dst = (uint4*)(z1b + ((size_t)(mt * 16 + row)) * DD + pch * 16);
    dst[0] = v0; dst[1] = v1;
  }
  #pragma unroll
  for (int o = 1; o < 16; o <<= 1)
    #pragma unroll
    for (int jt = 0; jt < 4; ++jt)
      #pragma unroll
      for (int q = 0; q < 4; ++q) {
        sS[jt][q] += __shfl_xor(sS[jt][q], o);
        sQ[jt][q] += __shfl_xor(sQ[jt][q], o);
      }
  if (lo == 0) {
    #pragma unroll
    for (int jt = 0; jt < 4; ++jt)
      #pragma unroll
      for (int q = 0; q < 4; ++q) {
        atomicAdd(&sred[jt * 16 + hi * 4 + q], sS[jt][q]);
        atomicAdd(&sred[64 + jt * 16 + hi * 4 + q], sQ[jt][q]);
      }
  }
  __syncthreads();
  if (threadIdx.x < 128) atomicAdd(&stats[threadIdx.x], sred[threadIdx.x]);
}

// ---------------- mlpB (MFMA): z2 = relu(BN1(z1))@W2 + b2, bf16 in-place + stats2 ----------------
__global__ __launch_bounds__(256) void k_mlpB(
    ushort* __restrict__ z1b, const ushort* __restrict__ wfrag,
    const float* __restrict__ bvec, const float* __restrict__ g1,
    const float* __restrict__ b1g, const float* __restrict__ statsIn,
    float* __restrict__ statsOut, float invN, int NT, int nwaves)
{
  __shared__ float sred[128];
  __shared__ float scl[DD], shl[DD];
  __shared__ ushort ldsT[4][16][72];
  if (threadIdx.x < 128) sred[threadIdx.x] = 0.f;
  if (threadIdx.x < DD) {
    int j = threadIdx.x;
    float m = statsIn[j] * invN;
    float v = statsIn[DD + j] * invN - m * m;
    float sc = rsqrtf(v + BNEPS) * g1[j];
    scl[j] = sc;
    shl[j] = b1g[j] - m * sc;
  }
  __syncthreads();
  int lane = threadIdx.x & 63;
  int wid = threadIdx.x >> 6;
  int gwave = blockIdx.x * 4 + wid;
  int hi = lane >> 4, lo = lane & 15;
  bhalf8 af[8];
  #pragma unroll
  for (int f = 0; f < 8; ++f)
    af[f] = *(const bhalf8*)(wfrag + f * 512 + lane * 8);
  float4 bq[4];
  #pragma unroll
  for (int jt = 0; jt < 4; ++jt)
    bq[jt] = *(const float4*)(bvec + jt * 16 + hi * 4);
  float4 scr[2][2], shr[2][2];
  #pragma unroll
  for (int kb = 0; kb < 2; ++kb) {
    int k0 = kb * 32 + hi * 8;
    scr[kb][0] = *(const float4*)&scl[k0];
    scr[kb][1] = *(const float4*)&scl[k0 + 4];
    shr[kb][0] = *(const float4*)&shl[k0];
    shr[kb][1] = *(const float4*)&shl[k0 + 4];
  }
  float sS[4][4] = {{0}}, sQ[4][4] = {{0}};
  for (int mt = gwave; mt < NT; mt += nwaves) {
    int node = mt * 16 + lo;
    const ushort* zrow = z1b + (size_t)node * DD;
    bhalf8 bfr[2];
    #pragma unroll
    for (int kb = 0; kb < 2; ++kb) {
      int k0 = kb * 32 + hi * 8;
      uint4 zv = *(const uint4*)(zrow + k0);
      float xr[8];
      xr[0] = __uint_as_float(zv.x << 16);
      xr[1] = __uint_as_float(zv.x & 0xFFFF0000u);
      xr[2] = __uint_as_float(zv.y << 16);
      xr[3] = __uint_as_float(zv.y & 0xFFFF0000u);
      xr[4] = __uint_as_float(zv.z << 16);
      xr[5] = __uint_as_float(zv.z & 0xFFFF0000u);
      xr[6] = __uint_as_float(zv.w << 16);
      xr[7] = __uint_as_float(zv.w & 0xFFFF0000u);
      xr[0] = fmaxf(fmaf(xr[0], scr[kb][0].x, shr[kb][0].x), 0.f);
      xr[1] = fmaxf(fmaf(xr[1], scr[kb][0].y, shr[kb][0].y), 0.f);
      xr[2] = fmaxf(fmaf(xr[2], scr[kb][0].z, shr[kb][0].z), 0.f);
      xr[3] = fmaxf(fmaf(xr[3], scr[kb][0].w, shr[kb][0].w), 0.f);
      xr[4] = fmaxf(fmaf(xr[4], scr[kb][1].x, shr[kb][1].x), 0.f);
      xr[5] = fmaxf(fmaf(xr[5], scr[kb][1].y, shr[kb][1].y), 0.f);
      xr[6] = fmaxf(fmaf(xr[6], scr[kb][1].z, shr[kb][1].z), 0.f);
      xr[7] = fmaxf(fmaf(xr[7], scr[kb][1].w, shr[kb][1].w), 0.f);
      bhalf8 b8;
      #pragma unroll
      for (int r = 0; r < 8; ++r) b8[r] = (short)f2bf(xr[r]);
      bfr[kb] = b8;
    }
    fx4 acc[4];
    #pragma unroll
    for (int jt = 0; jt < 4; ++jt) {
      fx4 a = {0.f, 0.f, 0.f, 0.f};
      a = __builtin_amdgcn_mfma_f32_16x16x32_bf16(af[jt * 2 + 0], bfr[0], a, 0, 0, 0);
      a = __builtin_amdgcn_mfma_f32_16x16x32_bf16(af[jt * 2 + 1], bfr[1], a, 0, 0, 0);
      acc[jt] = a;
    }
    #pragma unroll
    for (int jt = 0; jt < 4; ++jt) {
      float z0 = acc[jt][0] + bq[jt].x;
      float z1 = acc[jt][1] + bq[jt].y;
      float z2 = acc[jt][2] + bq[jt].z;
      float z3 = acc[jt][3] + bq[jt].w;
      sS[jt][0] += z0; sQ[jt][0] += z0 * z0;
      sS[jt][1] += z1; sQ[jt][1] += z1 * z1;
      sS[jt][2] += z2; sQ[jt][2] += z2 * z2;
      sS[jt][3] += z3; sQ[jt][3] += z3 * z3;
      uint p0 = ((uint)f2bf(z1) << 16) | f2bf(z0);
      uint p1 = ((uint)f2bf(z3) << 16) | f2bf(z2);
      int jphys = jt ^ (lo & 3);
      *(uint2*)&ldsT[wid][lo][jphys * 16 + hi * 4] = make_uint2(p0, p1);
    }
    int row = lane >> 2, pch = lane & 3;
    int pphys = pch ^ (row & 3);
    const uint4* src = (const uint4*)&ldsT[wid][row][pphys * 16];
    uint4 v0 = src[0], v1 = src[1];
    uint4* dst = (uint4*)(z1b + ((size_t)(mt * 16 + row)) * DD + pch * 16);
    dst[0] = v0; dst[1] = v1;
  }
  #pragma unroll
  for (int o = 1; o < 16; o <<= 1)
    #pragma unroll
    for (int jt = 0; jt < 4; ++jt)
      #pragma unroll
      for (int q = 0; q < 4; ++q) {
        sS[jt][q] += __shfl_xor(sS[jt][q], o);
        sQ[jt][q] += __shfl_xor(sQ[jt][q], o);
      }
  if (lo == 0) {
    #pragma unroll
    for (int jt = 0; jt < 4; ++jt)
      #pragma unroll
      for (int q = 0; q < 4; ++q) {
        atomicAdd(&sred[jt * 16 + hi * 4 + q], sS[jt][q]);
        atomicAdd(&sred[64 + jt * 16 + hi * 4 + q], sQ[jt][q]);
      }
  }
  __syncthreads();
  if (threadIdx.x < 128) atomicAdd(&statsOut[threadIdx.x], sred[threadIdx.x]);
}

// ---------------- bnout + fingerprint: block per graph, bf16 in, slab h2 out ----------------
__global__ __launch_bounds__(256) void k_bnout_fp(
    const ushort* __restrict__ zb, ushort* __restrict__ h2,
    const float* __restrict__ g2, const float* __restrict__ b2g,
    const float* __restrict__ statsIn, const int* __restrict__ gs,
    float* __restrict__ fp, float* __restrict__ outp,
    int l, float invN, int N)
{
  __shared__ float sc[DD], sh[DD], part[4 * DD];
  int tid = threadIdx.x;
  if (tid < DD) {
    float m = statsIn[tid] * invN;
    float v = statsIn[DD + tid] * invN - m * m;
    float inv = rsqrtf(v + BNEPS);
    float scale = inv * g2[tid];
    sc[tid] = scale;
    sh[tid] = b2g[tid] - m * scale;
  }
  __syncthreads();
  int g = blockIdx.x;
  int r0 = gs[g], r1 = gs[g + 1];
  int ch = tid & 63, rg = tid >> 6;
  bool last = (l == LL - 1);
  int slab = ch >> 4;
  ushort* hdst = h2 + (size_t)slab * N * SCH + (ch & 15);
  float facc = 0.f;
  for (int r = r0 + rg; r < r1; r += 4) {
    float z = bf2f(zb[(size_t)r * DD + ch]);
    float y = z * sc[ch] + sh[ch];
    if (!last) y = fmaxf(y, 0.f);
    hdst[(size_t)r * SCH] = f2bf(y);
    if (last) outp[(size_t)r * DD + ch] = y;
    facc += y;
  }
  part[rg * DD + ch] = facc;
  __syncthreads();
  if (tid < DD) {
    float s = part[tid] + part[DD + tid] + part[2 * DD + tid] + part[3 * DD + tid];
    fp[((size_t)g * LL + l) * DD + tid] = s;
  }
}

extern "C" void kernel_launch(void* const* d_in, const int* in_sizes, int n_in,
                              void* d_out, int out_size, void* d_ws, size_t ws_size,
                              hipStream_t stream)
{
  const int*   x_feats    = (const int*)d_in[0];
  const int*   edge_index = (const int*)d_in[1];
  const int*   edge_attr  = (const int*)d_in[2];
  const int*   batch      = (const int*)d_in[3];
  const float* atom_emb   = (const float*)d_in[4];
  const float* bond_emb   = (const float*)d_in[5];
  const float* eps        = (const float*)d_in[6];
  const float* W1         = (const float*)d_in[7];
  const float* b1         = (const float*)d_in[8];
  const float* bn1_g      = (const float*)d_in[9];
  const float* bn1_b      = (const float*)d_in[10];
  const float* W2         = (const float*)d_in[11];
  const float* b2         = (const float*)d_in[12];
  const float* bn_g       = (const float*)d_in[13];
  const float* bn_b       = (const float*)d_in[14];

  int N = in_sizes[3];
  int E = in_sizes[1] / 2;
  int NB = (N + SCB - 1) / SCB;
  int NT = N >> 4;
  float invN = 1.f / (float)N;

  float* out = (float*)d_out;
  float* fp  = out + (size_t)N * DD;

  float* buf     = (float*)d_ws;                 // N*D fp32 (agg)
  float* stats   = buf + (size_t)N * DD;         // L*256
  float* bcomb   = stats + LL * 256;             // L*216*D
  ushort* h2     = (ushort*)(bcomb + LL * 216 * DD); // 4 slabs × N×16 bf16
  ushort* z1b    = h2 + (size_t)N * DD;          // N*D bf16 (z1 -> z2)
  ushort* wfrag  = z1b + (size_t)N * DD;         // L*2*4096
  int* deg       = (int*)(wfrag + LL * 2 * 4096);// N
  int* rank      = deg + N;                      // E
  int* scanned   = rank + E;                     // N
  int* bsum      = scanned + N;                  // 128
  int* boff      = bsum + 128;                   // 128
  int* gs        = boff + 128;                   // G+1
  int* rcarr     = gs + (GG + 1);                // E

  hipMemsetAsync(stats, 0, LL * 256 * sizeof(float), stream);
  hipMemsetAsync(deg, 0, (size_t)N * sizeof(int), stream);

  k_atom<<<(N * 16 + 255) / 256, 256, 0, stream>>>(x_feats, atom_emb, h2, N);
  k_hist<<<(E + 255) / 256, 256, 0, stream>>>(edge_index, deg, rank, E);
  k_scan1<<<NB, SCB, 0, stream>>>(deg, scanned, bsum, N);
  k_scan2<<<1, 128, 0, stream>>>(bsum, boff, NB);
  k_fill<<<(E + 255) / 256, 256, 0, stream>>>(edge_index, edge_attr, scanned,
                                              boff, rank, rcarr, E);
  k_bcomb<<<(LL * 216 * DD + 255) / 256, 256, 0, stream>>>(bond_emb, bcomb);
  k_bounds<<<(GG + 256) / 256, 256, 0, stream>>>(batch, gs, N);
  k_wprep<<<(LL * 2 * 4096 + 255) / 256, 256, 0, stream>>>(W1, W2, wfrag);

  const int gridM = 640;
  const int nwaves = gridM * 4;
  for (int l = 0; l < LL; ++l) {
    float* s1 = stats + l * 256;
    float* s2 = s1 + 128;
    for (int p = 0; p < NSLAB; ++p)
      k_gather<<<(N + 3) / 4, 256, 0, stream>>>(h2, rcarr, scanned, boff,
                                                bcomb + (size_t)l * 216 * DD,
                                                buf, N, E, p);
    k_mlpA<<<gridM, 256, 0, stream>>>(h2, buf, wfrag + (size_t)(l * 2 + 0) * 4096,
                                      b1 + l * DD, eps + l, z1b, s1, N, NT, nwaves);
    k_mlpB<<<gridM, 256, 0, stream>>>(z1b, wfrag + (size_t)(l * 2 + 1) * 4096,
                                      b2 + l * DD, bn1_g + l * DD, bn1_b + l * DD,
                                      s1, s2, invN, NT, nwaves);
    k_bnout_fp<<<GG, 256, 0, stream>>>(z1b, h2, bn_g + l * DD, bn_b + l * DD,
                                       s2, gs, fp, out, l, invN, N);
  }
}

// Round 10
// 847.504 us; speedup vs baseline: 1.3404x; 1.3404x over previous
//
#include <hip/hip_runtime.h>

#define DD 64
#define LL 5
#define GG 512
#define AFN 9
#define AVN 120
#define BFN 3
#define BVN 6
#define BNEPS 1e-5f
#define SCB 1024
#define NCPY 8           // per-XCD histogram copies

typedef unsigned int uint;
typedef unsigned short ushort;
typedef short bhalf8 __attribute__((ext_vector_type(8)));
typedef float fx4 __attribute__((ext_vector_type(4)));

__device__ inline ushort f2bf(float f) {
  uint u = __float_as_uint(f);
  uint r = (u + 0x7FFF + ((u >> 16) & 1)) >> 16;   // round-to-nearest-even
  return (ushort)r;
}
__device__ inline float bf2f(ushort u) { return __uint_as_float(((uint)u) << 16); }

// ---------------- atom encoder: h2 bf16 only ----------------
__global__ __launch_bounds__(256) void k_atom(
    const int* __restrict__ xf, const float* __restrict__ aemb,
    ushort* __restrict__ h2, int N)
{
  int t = blockIdx.x * 256 + threadIdx.x;
  int row = t >> 4, c4 = t & 15;
  if (row >= N) return;
  const int* x = xf + row * AFN;
  float4 s = make_float4(0.f, 0.f, 0.f, 0.f);
  #pragma unroll
  for (int f = 0; f < AFN; ++f) {
    int v = x[f];
    float4 w = ((const float4*)aemb)[(f * AVN + v) * 16 + c4];
    s.x += w.x; s.y += w.y; s.z += w.z; s.w += w.w;
  }
  ushort4 p;
  p.x = f2bf(s.x); p.y = f2bf(s.y); p.z = f2bf(s.z); p.w = f2bf(s.w);
  ((ushort4*)h2)[row * 16 + c4] = p;
}

// ---------------- CSR build: per-XCD privatized histogram ----------------
__global__ __launch_bounds__(256) void k_hist(const int* __restrict__ ei,
    int* __restrict__ deg8, int* __restrict__ rank, int E, int N)
{
  int t = blockIdx.x * 256 + threadIdx.x;
  if (t >= E) return;
  int copy = blockIdx.x & (NCPY - 1);
  rank[t] = atomicAdd(&deg8[copy * N + ei[E + t]], 1);
}

// fold 8 copies: in-place per-copy exclusive bases + block scan of totals
__global__ __launch_bounds__(1024) void k_scan1(int* __restrict__ deg8,
    int* __restrict__ scanned, int* __restrict__ bsum, int N)
{
  __shared__ int s[SCB];
  int i = blockIdx.x * SCB + threadIdx.x;
  int tot = 0;
  if (i < N) {
    int acc = 0;
    #pragma unroll
    for (int x = 0; x < NCPY; ++x) {
      int d = deg8[x * N + i];
      deg8[x * N + i] = acc;      // per-copy base within this node's segment
      acc += d;
    }
    tot = acc;
  }
  s[threadIdx.x] = tot;
  for (int off = 1; off < SCB; off <<= 1) {
    __syncthreads();
    int v = (threadIdx.x >= off) ? s[threadIdx.x - off] : 0;
    __syncthreads();
    s[threadIdx.x] += v;
  }
  __syncthreads();
  if (i < N) scanned[i] = s[threadIdx.x] - tot;
  if (threadIdx.x == SCB - 1) bsum[blockIdx.x] = s[SCB - 1];
}

__global__ __launch_bounds__(128) void k_scan2(const int* __restrict__ bsum,
    int* __restrict__ boff, int NB)
{
  __shared__ int s[128];
  int x = (threadIdx.x < NB) ? bsum[threadIdx.x] : 0;
  s[threadIdx.x] = x;
  for (int off = 1; off < 128; off <<= 1) {
    __syncthreads();
    int v = (threadIdx.x >= off) ? s[threadIdx.x - off] : 0;
    __syncthreads();
    s[threadIdx.x] += v;
  }
  __syncthreads();
  if (threadIdx.x < NB) boff[threadIdx.x] = s[threadIdx.x] - x;
}

__global__ __launch_bounds__(256) void k_fill(const int* __restrict__ ei,
    const int* __restrict__ ea, const int* __restrict__ scanned,
    const int* __restrict__ boff, const int* __restrict__ rank,
    const int* __restrict__ deg8, int* __restrict__ rcarr, int E, int N)
{
  int t = blockIdx.x * 256 + threadIdx.x;
  if (t >= E) return;
  int r = ei[t], c = ei[E + t];
  int copy = (t >> 8) & (NCPY - 1);
  int code = ea[t * 3 + 0] + ea[t * 3 + 1] * 6 + ea[t * 3 + 2] * 36;
  int pos = scanned[c] + boff[c >> 10] + deg8[copy * N + c] + rank[t];
  rcarr[pos] = r | (code << 20);
}

__global__ __launch_bounds__(256) void k_bcomb(const float* __restrict__ bemb,
    float* __restrict__ bcomb)
{
  int t = blockIdx.x * 256 + threadIdx.x;
  if (t >= LL * 216 * DD) return;
  int ch = t & 63;
  int cl = t >> 6;
  int code = cl % 216;
  int l = cl / 216;
  int a0 = code % 6, a1 = (code / 6) % 6, a2 = code / 36;
  const float* B = bemb + (size_t)l * BFN * BVN * DD;
  bcomb[t] = B[(0 * BVN + a0) * DD + ch] + B[(1 * BVN + a1) * DD + ch]
           + B[(2 * BVN + a2) * DD + ch];
}

__global__ __launch_bounds__(256) void k_bounds(const int* __restrict__ batch,
    int* __restrict__ gs, int N)
{
  int g = blockIdx.x * 256 + threadIdx.x;
  if (g > GG) return;
  int lo = 0, hi = N;
  while (lo < hi) { int mid = (lo + hi) >> 1; if (batch[mid] < g) lo = mid + 1; else hi = mid; }
  gs[g] = lo;
}

// W fragments: [l][wsel][jt][kb][lane][r] -> bf16(W[kb*32+(lane>>4)*8+r][jt*16+(lane&15)])
__global__ __launch_bounds__(256) void k_wprep(const float* __restrict__ W1,
    const float* __restrict__ W2, ushort* __restrict__ wfrag)
{
  int t = blockIdx.x * 256 + threadIdx.x;
  if (t >= LL * 2 * 4096) return;
  int r = t & 7;
  int lane = (t >> 3) & 63;
  int kb = (t >> 9) & 1;
  int jt = (t >> 10) & 3;
  int wsel = (t >> 12) & 1;
  int l = t >> 13;
  int k = kb * 32 + ((lane >> 4) & 3) * 8 + r;
  int j = jt * 16 + (lane & 15);
  const float* Ws = (wsel ? W2 : W1) + (size_t)l * DD * DD;
  wfrag[t] = f2bf(Ws[k * DD + j]);
}

// ---------------- per-layer aggregate (round-8 proven form) ----------------
__global__ __launch_bounds__(256) void k_gather(
    const ushort* __restrict__ h2, const int* __restrict__ rcarr,
    const int* __restrict__ scanned, const int* __restrict__ boff,
    const float* __restrict__ bc, float* __restrict__ agg, int N, int E)
{
  int lane = threadIdx.x & 63;
  int node = blockIdx.x * 4 + (threadIdx.x >> 6);
  if (node >= N) return;
  int s = scanned[node] + boff[node >> 10];
  int e = (node + 1 < N) ? (scanned[node + 1] + boff[(node + 1) >> 10]) : E;
  int sub = lane >> 4;
  int c4 = lane & 15;
  float a0 = 0.f, a1 = 0.f, a2 = 0.f, a3 = 0.f;
  const uint2* h2v = (const uint2*)h2;
  const float4* bc4 = (const float4*)bc;
  for (int k0 = s; k0 < e; k0 += 4) {
    int idx = k0 + sub;
    bool valid = idx < e;
    int rck = rcarr[valid ? idx : s];
    int r = rck & 0xFFFFF;
    int code = (rck >> 20) & 0xFFF;
    uint2 hv = h2v[r * 16 + c4];
    float4 bv = bc4[code * 16 + c4];
    float f0 = __uint_as_float(hv.x << 16);
    float f1 = __uint_as_float(hv.x & 0xFFFF0000u);
    float f2 = __uint_as_float(hv.y << 16);
    float f3 = __uint_as_float(hv.y & 0xFFFF0000u);
    float m0 = fmaxf(f0 + bv.x, 0.f);
    float m1 = fmaxf(f1 + bv.y, 0.f);
    float m2 = fmaxf(f2 + bv.z, 0.f);
    float m3 = fmaxf(f3 + bv.w, 0.f);
    if (valid) { a0 += m0; a1 += m1; a2 += m2; a3 += m3; }
  }
  a0 += __shfl_xor(a0, 16); a1 += __shfl_xor(a1, 16);
  a2 += __shfl_xor(a2, 16); a3 += __shfl_xor(a3, 16);
  a0 += __shfl_xor(a0, 32); a1 += __shfl_xor(a1, 32);
  a2 += __shfl_xor(a2, 32); a3 += __shfl_xor(a3, 32);
  if (sub == 0)
    ((float4*)agg)[(size_t)node * 16 + c4] = make_float4(a0, a1, a2, a3);
}

// ---------------- mlpA (MFMA): z1 = ((1+eps)h + agg)@W1 + b1, bf16 out + stats ----------------
__global__ __launch_bounds__(256) void k_mlpA(
    const ushort* __restrict__ h2, const float* __restrict__ agg,
    const ushort* __restrict__ wfrag, const float* __restrict__ bvec,
    const float* __restrict__ epsl, ushort* __restrict__ z1b,
    float* __restrict__ stats, int NT, int nwaves)
{
  __shared__ float sred[128];
  __shared__ ushort ldsT[4][16][72];
  if (threadIdx.x < 128) sred[threadIdx.x] = 0.f;
  __syncthreads();
  int lane = threadIdx.x & 63;
  int wid = threadIdx.x >> 6;
  int gwave = blockIdx.x * 4 + wid;
  int hi = lane >> 4, lo = lane & 15;
  float epsv = 1.f + epsl[0];
  bhalf8 af[8];
  #pragma unroll
  for (int f = 0; f < 8; ++f)
    af[f] = *(const bhalf8*)(wfrag + f * 512 + lane * 8);
  float4 bq[4];
  #pragma unroll
  for (int jt = 0; jt < 4; ++jt)
    bq[jt] = *(const float4*)(bvec + jt * 16 + hi * 4);
  float sS[4][4] = {{0}}, sQ[4][4] = {{0}};
  for (int mt = gwave; mt < NT; mt += nwaves) {
    int node = mt * 16 + lo;
    const ushort* hrow = h2 + (size_t)node * DD;
    const float* arow = agg + (size_t)node * DD;
    bhalf8 bfr[2];
    #pragma unroll
    for (int kb = 0; kb < 2; ++kb) {
      int k0 = kb * 32 + hi * 8;
      uint4 hv = *(const uint4*)(hrow + k0);
      float4 aa = *(const float4*)(arow + k0);
      float4 ab = *(const float4*)(arow + k0 + 4);
      float xr[8];
      xr[0] = fmaf(epsv, __uint_as_float(hv.x << 16), aa.x);
      xr[1] = fmaf(epsv, __uint_as_float(hv.x & 0xFFFF0000u), aa.y);
      xr[2] = fmaf(epsv, __uint_as_float(hv.y << 16), aa.z);
      xr[3] = fmaf(epsv, __uint_as_float(hv.y & 0xFFFF0000u), aa.w);
      xr[4] = fmaf(epsv, __uint_as_float(hv.z << 16), ab.x);
      xr[5] = fmaf(epsv, __uint_as_float(hv.z & 0xFFFF0000u), ab.y);
      xr[6] = fmaf(epsv, __uint_as_float(hv.w << 16), ab.z);
      xr[7] = fmaf(epsv, __uint_as_float(hv.w & 0xFFFF0000u), ab.w);
      bhalf8 b8;
      #pragma unroll
      for (int r = 0; r < 8; ++r) b8[r] = (short)f2bf(xr[r]);
      bfr[kb] = b8;
    }
    fx4 acc[4];
    #pragma unroll
    for (int jt = 0; jt < 4; ++jt) {
      fx4 a = {0.f, 0.f, 0.f, 0.f};
      a = __builtin_amdgcn_mfma_f32_16x16x32_bf16(af[jt * 2 + 0], bfr[0], a, 0, 0, 0);
      a = __builtin_amdgcn_mfma_f32_16x16x32_bf16(af[jt * 2 + 1], bfr[1], a, 0, 0, 0);
      acc[jt] = a;
    }
    #pragma unroll
    for (int jt = 0; jt < 4; ++jt) {
      float z0 = acc[jt][0] + bq[jt].x;
      float z1 = acc[jt][1] + bq[jt].y;
      float z2 = acc[jt][2] + bq[jt].z;
      float z3 = acc[jt][3] + bq[jt].w;
      sS[jt][0] += z0; sQ[jt][0] += z0 * z0;
      sS[jt][1] += z1; sQ[jt][1] += z1 * z1;
      sS[jt][2] += z2; sQ[jt][2] += z2 * z2;
      sS[jt][3] += z3; sQ[jt][3] += z3 * z3;
      uint p0 = ((uint)f2bf(z1) << 16) | f2bf(z0);
      uint p1 = ((uint)f2bf(z3) << 16) | f2bf(z2);
      int jphys = jt ^ (lo & 3);
      *(uint2*)&ldsT[wid][lo][jphys * 16 + hi * 4] = make_uint2(p0, p1);
    }
    int row = lane >> 2, pch = lane & 3;
    int pphys = pch ^ (row & 3);
    const uint4* src = (const uint4*)&ldsT[wid][row][pphys * 16];
    uint4 v0 = src[0], v1 = src[1];
    uint4* dst = (uint4*)(z1b + ((size_t)(mt * 16 + row)) * DD + pch * 16);
    dst[0] = v0; dst[1] = v1;
  }
  #pragma unroll
  for (int o = 1; o < 16; o <<= 1)
    #pragma unroll
    for (int jt = 0; jt < 4; ++jt)
      #pragma unroll
      for (int q = 0; q < 4; ++q) {
        sS[jt][q] += __shfl_xor(sS[jt][q], o);
        sQ[jt][q] += __shfl_xor(sQ[jt][q], o);
      }
  if (lo == 0) {
    #pragma unroll
    for (int jt = 0; jt < 4; ++jt)
      #pragma unroll
      for (int q = 0; q < 4; ++q) {
        atomicAdd(&sred[jt * 16 + hi * 4 + q], sS[jt][q]);
        atomicAdd(&sred[64 + jt * 16 + hi * 4 + q], sQ[jt][q]);
      }
  }
  __syncthreads();
  if (threadIdx.x < 128) atomicAdd(&stats[threadIdx.x], sred[threadIdx.x]);
}

// ---------------- mlpB (MFMA): z2 = relu(BN1(z1))@W2 + b2, bf16 in-place + stats2 ----------------
__global__ __launch_bounds__(256) void k_mlpB(
    ushort* __restrict__ z1b, const ushort* __restrict__ wfrag,
    const float* __restrict__ bvec, const float* __restrict__ g1,
    const float* __restrict__ b1g, const float* __restrict__ statsIn,
    float* __restrict__ statsOut, float invN, int NT, int nwaves)
{
  __shared__ float sred[128];
  __shared__ float scl[DD], shl[DD];
  __shared__ ushort ldsT[4][16][72];
  if (threadIdx.x < 128) sred[threadIdx.x] = 0.f;
  if (threadIdx.x < DD) {
    int j = threadIdx.x;
    float m = statsIn[j] * invN;
    float v = statsIn[DD + j] * invN - m * m;
    float sc = rsqrtf(v + BNEPS) * g1[j];
    scl[j] = sc;
    shl[j] = b1g[j] - m * sc;
  }
  __syncthreads();
  int lane = threadIdx.x & 63;
  int wid = threadIdx.x >> 6;
  int gwave = blockIdx.x * 4 + wid;
  int hi = lane >> 4, lo = lane & 15;
  bhalf8 af[8];
  #pragma unroll
  for (int f = 0; f < 8; ++f)
    af[f] = *(const bhalf8*)(wfrag + f * 512 + lane * 8);
  float4 bq[4];
  #pragma unroll
  for (int jt = 0; jt < 4; ++jt)
    bq[jt] = *(const float4*)(bvec + jt * 16 + hi * 4);
  float4 scr[2][2], shr[2][2];
  #pragma unroll
  for (int kb = 0; kb < 2; ++kb) {
    int k0 = kb * 32 + hi * 8;
    scr[kb][0] = *(const float4*)&scl[k0];
    scr[kb][1] = *(const float4*)&scl[k0 + 4];
    shr[kb][0] = *(const float4*)&shl[k0];
    shr[kb][1] = *(const float4*)&shl[k0 + 4];
  }
  float sS[4][4] = {{0}}, sQ[4][4] = {{0}};
  for (int mt = gwave; mt < NT; mt += nwaves) {
    int node = mt * 16 + lo;
    const ushort* zrow = z1b + (size_t)node * DD;
    bhalf8 bfr[2];
    #pragma unroll
    for (int kb = 0; kb < 2; ++kb) {
      int k0 = kb * 32 + hi * 8;
      uint4 zv = *(const uint4*)(zrow + k0);
      float xr[8];
      xr[0] = __uint_as_float(zv.x << 16);
      xr[1] = __uint_as_float(zv.x & 0xFFFF0000u);
      xr[2] = __uint_as_float(zv.y << 16);
      xr[3] = __uint_as_float(zv.y & 0xFFFF0000u);
      xr[4] = __uint_as_float(zv.z << 16);
      xr[5] = __uint_as_float(zv.z & 0xFFFF0000u);
      xr[6] = __uint_as_float(zv.w << 16);
      xr[7] = __uint_as_float(zv.w & 0xFFFF0000u);
      xr[0] = fmaxf(fmaf(xr[0], scr[kb][0].x, shr[kb][0].x), 0.f);
      xr[1] = fmaxf(fmaf(xr[1], scr[kb][0].y, shr[kb][0].y), 0.f);
      xr[2] = fmaxf(fmaf(xr[2], scr[kb][0].z, shr[kb][0].z), 0.f);
      xr[3] = fmaxf(fmaf(xr[3], scr[kb][0].w, shr[kb][0].w), 0.f);
      xr[4] = fmaxf(fmaf(xr[4], scr[kb][1].x, shr[kb][1].x), 0.f);
      xr[5] = fmaxf(fmaf(xr[5], scr[kb][1].y, shr[kb][1].y), 0.f);
      xr[6] = fmaxf(fmaf(xr[6], scr[kb][1].z, shr[kb][1].z), 0.f);
      xr[7] = fmaxf(fmaf(xr[7], scr[kb][1].w, shr[kb][1].w), 0.f);
      bhalf8 b8;
      #pragma unroll
      for (int r = 0; r < 8; ++r) b8[r] = (short)f2bf(xr[r]);
      bfr[kb] = b8;
    }
    fx4 acc[4];
    #pragma unroll
    for (int jt = 0; jt < 4; ++jt) {
      fx4 a = {0.f, 0.f, 0.f, 0.f};
      a = __builtin_amdgcn_mfma_f32_16x16x32_bf16(af[jt * 2 + 0], bfr[0], a, 0, 0, 0);
      a = __builtin_amdgcn_mfma_f32_16x16x32_bf16(af[jt * 2 + 1], bfr[1], a, 0, 0, 0);
      acc[jt] = a;
    }
    #pragma unroll
    for (int jt = 0; jt < 4; ++jt) {
      float z0 = acc[jt][0] + bq[jt].x;
      float z1 = acc[jt][1] + bq[jt].y;
      float z2 = acc[jt][2] + bq[jt].z;
      float z3 = acc[jt][3] + bq[jt].w;
      sS[jt][0] += z0; sQ[jt][0] += z0 * z0;
      sS[jt][1] += z1; sQ[jt][1] += z1 * z1;
      sS[jt][2] += z2; sQ[jt][2] += z2 * z2;
      sS[jt][3] += z3; sQ[jt][3] += z3 * z3;
      uint p0 = ((uint)f2bf(z1) << 16) | f2bf(z0);
      uint p1 = ((uint)f2bf(z3) << 16) | f2bf(z2);
      int jphys = jt ^ (lo & 3);
      *(uint2*)&ldsT[wid][lo][jphys * 16 + hi * 4] = make_uint2(p0, p1);
    }
    int row = lane >> 2, pch = lane & 3;
    int pphys = pch ^ (row & 3);
    const uint4* src = (const uint4*)&ldsT[wid][row][pphys * 16];
    uint4 v0 = src[0], v1 = src[1];
    uint4* dst = (uint4*)(z1b + ((size_t)(mt * 16 + row)) * DD + pch * 16);
    dst[0] = v0; dst[1] = v1;
  }
  #pragma unroll
  for (int o = 1; o < 16; o <<= 1)
    #pragma unroll
    for (int jt = 0; jt < 4; ++jt)
      #pragma unroll
      for (int q = 0; q < 4; ++q) {
        sS[jt][q] += __shfl_xor(sS[jt][q], o);
        sQ[jt][q] += __shfl_xor(sQ[jt][q], o);
      }
  if (lo == 0) {
    #pragma unroll
    for (int jt = 0; jt < 4; ++jt)
      #pragma unroll
      for (int q = 0; q < 4; ++q) {
        atomicAdd(&sred[jt * 16 + hi * 4 + q], sS[jt][q]);
        atomicAdd(&sred[64 + jt * 16 + hi * 4 + q], sQ[jt][q]);
      }
  }
  __syncthreads();
  if (threadIdx.x < 128) atomicAdd(&statsOut[threadIdx.x], sred[threadIdx.x]);
}

// ---------------- bnout + fingerprint: block per graph, bf16 in ----------------
__global__ __launch_bounds__(256) void k_bnout_fp(
    const ushort* __restrict__ zb, ushort* __restrict__ h2,
    const float* __restrict__ g2, const float* __restrict__ b2g,
    const float* __restrict__ statsIn, const int* __restrict__ gs,
    float* __restrict__ fp, float* __restrict__ outp,
    int l, float invN)
{
  __shared__ float sc[DD], sh[DD], part[4 * DD];
  int tid = threadIdx.x;
  if (tid < DD) {
    float m = statsIn[tid] * invN;
    float v = statsIn[DD + tid] * invN - m * m;
    float inv = rsqrtf(v + BNEPS);
    float scale = inv * g2[tid];
    sc[tid] = scale;
    sh[tid] = b2g[tid] - m * scale;
  }
  __syncthreads();
  int g = blockIdx.x;
  int r0 = gs[g], r1 = gs[g + 1];
  int ch = tid & 63, rg = tid >> 6;
  bool last = (l == LL - 1);
  float facc = 0.f;
  for (int r = r0 + rg; r < r1; r += 4) {
    float z = bf2f(zb[(size_t)r * DD + ch]);
    float y = z * sc[ch] + sh[ch];
    if (!last) y = fmaxf(y, 0.f);
    h2[(size_t)r * DD + ch] = f2bf(y);
    if (last) outp[(size_t)r * DD + ch] = y;
    facc += y;
  }
  part[rg * DD + ch] = facc;
  __syncthreads();
  if (tid < DD) {
    float s = part[tid] + part[DD + tid] + part[2 * DD + tid] + part[3 * DD + tid];
    fp[((size_t)g * LL + l) * DD + tid] = s;
  }
}

extern "C" void kernel_launch(void* const* d_in, const int* in_sizes, int n_in,
                              void* d_out, int out_size, void* d_ws, size_t ws_size,
                              hipStream_t stream)
{
  const int*   x_feats    = (const int*)d_in[0];
  const int*   edge_index = (const int*)d_in[1];
  const int*   edge_attr  = (const int*)d_in[2];
  const int*   batch      = (const int*)d_in[3];
  const float* atom_emb   = (const float*)d_in[4];
  const float* bond_emb   = (const float*)d_in[5];
  const float* eps        = (const float*)d_in[6];
  const float* W1         = (const float*)d_in[7];
  const float* b1         = (const float*)d_in[8];
  const float* bn1_g      = (const float*)d_in[9];
  const float* bn1_b      = (const float*)d_in[10];
  const float* W2         = (const float*)d_in[11];
  const float* b2         = (const float*)d_in[12];
  const float* bn_g       = (const float*)d_in[13];
  const float* bn_b       = (const float*)d_in[14];

  int N = in_sizes[3];
  int E = in_sizes[1] / 2;
  int NB = (N + SCB - 1) / SCB;
  int NT = N >> 4;
  float invN = 1.f / (float)N;

  float* out = (float*)d_out;
  float* fp  = out + (size_t)N * DD;

  float* buf     = (float*)d_ws;                 // N*D fp32 (agg)
  float* stats   = buf + (size_t)N * DD;         // L*256
  float* bcomb   = stats + LL * 256;             // L*216*D
  ushort* h2     = (ushort*)(bcomb + LL * 216 * DD); // N*D bf16
  ushort* z1b    = h2 + (size_t)N * DD;          // N*D bf16 (z1 -> z2)
  ushort* wfrag  = z1b + (size_t)N * DD;         // L*2*4096
  int* deg8      = (int*)(wfrag + LL * 2 * 4096);// NCPY*N
  int* rank      = deg8 + NCPY * (size_t)N;      // E
  int* scanned   = rank + E;                     // N
  int* bsum      = scanned + N;                  // 128
  int* boff      = bsum + 128;                   // 128
  int* gs        = boff + 128;                   // G+1
  int* rcarr     = gs + (GG + 1);                // E

  hipMemsetAsync(stats, 0, LL * 256 * sizeof(float), stream);
  hipMemsetAsync(deg8, 0, NCPY * (size_t)N * sizeof(int), stream);

  k_atom<<<(N * 16 + 255) / 256, 256, 0, stream>>>(x_feats, atom_emb, h2, N);
  k_hist<<<(E + 255) / 256, 256, 0, stream>>>(edge_index, deg8, rank, E, N);
  k_scan1<<<NB, SCB, 0, stream>>>(deg8, scanned, bsum, N);
  k_scan2<<<1, 128, 0, stream>>>(bsum, boff, NB);
  k_fill<<<(E + 255) / 256, 256, 0, stream>>>(edge_index, edge_attr, scanned,
                                              boff, rank, deg8, rcarr, E, N);
  k_bcomb<<<(LL * 216 * DD + 255) / 256, 256, 0, stream>>>(bond_emb, bcomb);
  k_bounds<<<(GG + 256) / 256, 256, 0, stream>>>(batch, gs, N);
  k_wprep<<<(LL * 2 * 4096 + 255) / 256, 256, 0, stream>>>(W1, W2, wfrag);

  const int gridM = 640;
  const int nwaves = gridM * 4;
  for (int l = 0; l < LL; ++l) {
    float* s1 = stats + l * 256;
    float* s2 = s1 + 128;
    k_gather<<<(N + 3) / 4, 256, 0, stream>>>(h2, rcarr, scanned, boff,
                                              bcomb + (size_t)l * 216 * DD, buf, N, E);
    k_mlpA<<<gridM, 256, 0, stream>>>(h2, buf, wfrag + (size_t)(l * 2 + 0) * 4096,
                                      b1 + l * DD, eps + l, z1b, s1, NT, nwaves);
    k_mlpB<<<gridM, 256, 0, stream>>>(z1b, wfrag + (size_t)(l * 2 + 1) * 4096,
                                      b2 + l * DD, bn1_g + l * DD, bn1_b + l * DD,
                                      s1, s2, invN, NT, nwaves);
    k_bnout_fp<<<GG, 256, 0, stream>>>(z1b, h2, bn_g + l * DD, bn_b + l * DD,
                                       s2, gs, fp, out, l, invN);
  }
}

// Round 11
// 810.540 us; speedup vs baseline: 1.4015x; 1.0456x over previous
//
#include <hip/hip_runtime.h>

#define DD 64
#define LL 5
#define GG 512
#define AFN 9
#define AVN 120
#define BFN 3
#define BVN 6
#define BNEPS 1e-5f
#define SCB 1024
#define NCPY 8           // per-XCD histogram copies

typedef unsigned int uint;
typedef unsigned short ushort;
typedef short bhalf8 __attribute__((ext_vector_type(8)));
typedef float fx4 __attribute__((ext_vector_type(4)));

__device__ inline ushort f2bf(float f) {
  uint u = __float_as_uint(f);
  uint r = (u + 0x7FFF + ((u >> 16) & 1)) >> 16;   // round-to-nearest-even
  return (ushort)r;
}
__device__ inline float bf2f(ushort u) { return __uint_as_float(((uint)u) << 16); }

// ---------------- atom encoder: h2 bf16 only ----------------
__global__ __launch_bounds__(256) void k_atom(
    const int* __restrict__ xf, const float* __restrict__ aemb,
    ushort* __restrict__ h2, int N)
{
  int t = blockIdx.x * 256 + threadIdx.x;
  int row = t >> 4, c4 = t & 15;
  if (row >= N) return;
  const int* x = xf + row * AFN;
  float4 s = make_float4(0.f, 0.f, 0.f, 0.f);
  #pragma unroll
  for (int f = 0; f < AFN; ++f) {
    int v = x[f];
    float4 w = ((const float4*)aemb)[(f * AVN + v) * 16 + c4];
    s.x += w.x; s.y += w.y; s.z += w.z; s.w += w.w;
  }
  ushort4 p;
  p.x = f2bf(s.x); p.y = f2bf(s.y); p.z = f2bf(s.z); p.w = f2bf(s.w);
  ((ushort4*)h2)[row * 16 + c4] = p;
}

// ---------------- CSR build: per-XCD privatized histogram ----------------
__global__ __launch_bounds__(256) void k_hist(const int* __restrict__ ei,
    int* __restrict__ deg8, int* __restrict__ rank, int E, int N)
{
  int t = blockIdx.x * 256 + threadIdx.x;
  if (t >= E) return;
  int copy = blockIdx.x & (NCPY - 1);
  rank[t] = atomicAdd(&deg8[copy * N + ei[E + t]], 1);
}

// fold 8 copies: in-place per-copy exclusive bases + block scan of totals
__global__ __launch_bounds__(1024) void k_scan1(int* __restrict__ deg8,
    int* __restrict__ scanned, int* __restrict__ bsum, int N)
{
  __shared__ int s[SCB];
  int i = blockIdx.x * SCB + threadIdx.x;
  int tot = 0;
  if (i < N) {
    int acc = 0;
    #pragma unroll
    for (int x = 0; x < NCPY; ++x) {
      int d = deg8[x * N + i];
      deg8[x * N + i] = acc;      // per-copy base within this node's segment
      acc += d;
    }
    tot = acc;
  }
  s[threadIdx.x] = tot;
  for (int off = 1; off < SCB; off <<= 1) {
    __syncthreads();
    int v = (threadIdx.x >= off) ? s[threadIdx.x - off] : 0;
    __syncthreads();
    s[threadIdx.x] += v;
  }
  __syncthreads();
  if (i < N) scanned[i] = s[threadIdx.x] - tot;
  if (threadIdx.x == SCB - 1) bsum[blockIdx.x] = s[SCB - 1];
}

__global__ __launch_bounds__(128) void k_scan2(const int* __restrict__ bsum,
    int* __restrict__ boff, int NB)
{
  __shared__ int s[128];
  int x = (threadIdx.x < NB) ? bsum[threadIdx.x] : 0;
  s[threadIdx.x] = x;
  for (int off = 1; off < 128; off <<= 1) {
    __syncthreads();
    int v = (threadIdx.x >= off) ? s[threadIdx.x - off] : 0;
    __syncthreads();
    s[threadIdx.x] += v;
  }
  __syncthreads();
  if (threadIdx.x < NB) boff[threadIdx.x] = s[threadIdx.x] - x;
}

__global__ __launch_bounds__(256) void k_fill(const int* __restrict__ ei,
    const int* __restrict__ ea, const int* __restrict__ scanned,
    const int* __restrict__ boff, const int* __restrict__ rank,
    const int* __restrict__ deg8, int* __restrict__ rcarr, int E, int N)
{
  int t = blockIdx.x * 256 + threadIdx.x;
  if (t >= E) return;
  int r = ei[t], c = ei[E + t];
  int copy = (t >> 8) & (NCPY - 1);
  int code = ea[t * 3 + 0] + ea[t * 3 + 1] * 6 + ea[t * 3 + 2] * 36;
  int pos = scanned[c] + boff[c >> 10] + deg8[copy * N + c] + rank[t];
  rcarr[pos] = r | (code << 20);
}

__global__ __launch_bounds__(256) void k_bcomb(const float* __restrict__ bemb,
    float* __restrict__ bcomb)
{
  int t = blockIdx.x * 256 + threadIdx.x;
  if (t >= LL * 216 * DD) return;
  int ch = t & 63;
  int cl = t >> 6;
  int code = cl % 216;
  int l = cl / 216;
  int a0 = code % 6, a1 = (code / 6) % 6, a2 = code / 36;
  const float* B = bemb + (size_t)l * BFN * BVN * DD;
  bcomb[t] = B[(0 * BVN + a0) * DD + ch] + B[(1 * BVN + a1) * DD + ch]
           + B[(2 * BVN + a2) * DD + ch];
}

__global__ __launch_bounds__(256) void k_bounds(const int* __restrict__ batch,
    int* __restrict__ gs, int N)
{
  int g = blockIdx.x * 256 + threadIdx.x;
  if (g > GG) return;
  int lo = 0, hi = N;
  while (lo < hi) { int mid = (lo + hi) >> 1; if (batch[mid] < g) lo = mid + 1; else hi = mid; }
  gs[g] = lo;
}

// W fragments: [l][wsel][jt][kb][lane][r] -> bf16(W[kb*32+(lane>>4)*8+r][jt*16+(lane&15)])
__global__ __launch_bounds__(256) void k_wprep(const float* __restrict__ W1,
    const float* __restrict__ W2, ushort* __restrict__ wfrag)
{
  int t = blockIdx.x * 256 + threadIdx.x;
  if (t >= LL * 2 * 4096) return;
  int r = t & 7;
  int lane = (t >> 3) & 63;
  int kb = (t >> 9) & 1;
  int jt = (t >> 10) & 3;
  int wsel = (t >> 12) & 1;
  int l = t >> 13;
  int k = kb * 32 + ((lane >> 4) & 3) * 8 + r;
  int j = jt * 16 + (lane & 15);
  const float* Ws = (wsel ? W2 : W1) + (size_t)l * DD * DD;
  wfrag[t] = f2bf(Ws[k * DD + j]);
}

// ---------------- aggregate: wave per NODE-PAIR, 2 independent chains/lane ----------------
__global__ __launch_bounds__(256) void k_gather(
    const ushort* __restrict__ h2, const int* __restrict__ rcarr,
    const int* __restrict__ scanned, const int* __restrict__ boff,
    const float* __restrict__ bc, float* __restrict__ agg, int N, int E)
{
  int lane = threadIdx.x & 63;
  int wv = blockIdx.x * 4 + (threadIdx.x >> 6);
  int n0 = wv * 2, n1 = n0 + 1;
  if (n0 >= N) return;
  int s0 = scanned[n0] + boff[n0 >> 10];
  int e0 = (n1 < N) ? (scanned[n1] + boff[n1 >> 10]) : E;
  int s1 = 0, e1 = 0;
  if (n1 < N) {
    s1 = e0;
    e1 = (n1 + 1 < N) ? (scanned[n1 + 1] + boff[(n1 + 1) >> 10]) : E;
  }
  int len0 = e0 - s0, len1 = e1 - s1;
  int maxlen = max(len0, len1);
  int sub = lane >> 4;        // edge slot 0..3
  int c4 = lane & 15;         // channel quad
  float a0 = 0.f, a1 = 0.f, a2 = 0.f, a3 = 0.f;
  float b0 = 0.f, b1 = 0.f, b2 = 0.f, b3 = 0.f;
  const uint2* h2v = (const uint2*)h2;
  const float4* bc4p = (const float4*)bc;
  for (int k = sub; k < maxlen; k += 4) {
    bool v0 = k < len0;
    bool v1 = k < len1;
    int rc0 = rcarr[v0 ? s0 + k : s0];
    int rc1 = rcarr[v1 ? s1 + k : s1];
    int r0 = rc0 & 0xFFFFF, c0 = (rc0 >> 20) & 0xFFF;
    int r1 = rc1 & 0xFFFFF, c1 = (rc1 >> 20) & 0xFFF;
    uint2 hv0 = h2v[r0 * 16 + c4];
    uint2 hv1 = h2v[r1 * 16 + c4];
    float4 bv0 = bc4p[c0 * 16 + c4];
    float4 bv1 = bc4p[c1 * 16 + c4];
    float p0 = fmaxf(__uint_as_float(hv0.x << 16) + bv0.x, 0.f);
    float p1 = fmaxf(__uint_as_float(hv0.x & 0xFFFF0000u) + bv0.y, 0.f);
    float p2 = fmaxf(__uint_as_float(hv0.y << 16) + bv0.z, 0.f);
    float p3 = fmaxf(__uint_as_float(hv0.y & 0xFFFF0000u) + bv0.w, 0.f);
    float q0 = fmaxf(__uint_as_float(hv1.x << 16) + bv1.x, 0.f);
    float q1 = fmaxf(__uint_as_float(hv1.x & 0xFFFF0000u) + bv1.y, 0.f);
    float q2 = fmaxf(__uint_as_float(hv1.y << 16) + bv1.z, 0.f);
    float q3 = fmaxf(__uint_as_float(hv1.y & 0xFFFF0000u) + bv1.w, 0.f);
    if (v0) { a0 += p0; a1 += p1; a2 += p2; a3 += p3; }
    if (v1) { b0 += q0; b1 += q1; b2 += q2; b3 += q3; }
  }
  a0 += __shfl_xor(a0, 16); a1 += __shfl_xor(a1, 16);
  a2 += __shfl_xor(a2, 16); a3 += __shfl_xor(a3, 16);
  b0 += __shfl_xor(b0, 16); b1 += __shfl_xor(b1, 16);
  b2 += __shfl_xor(b2, 16); b3 += __shfl_xor(b3, 16);
  a0 += __shfl_xor(a0, 32); a1 += __shfl_xor(a1, 32);
  a2 += __shfl_xor(a2, 32); a3 += __shfl_xor(a3, 32);
  b0 += __shfl_xor(b0, 32); b1 += __shfl_xor(b1, 32);
  b2 += __shfl_xor(b2, 32); b3 += __shfl_xor(b3, 32);
  if (sub == 0)
    ((float4*)agg)[(size_t)n0 * 16 + c4] = make_float4(a0, a1, a2, a3);
  if (sub == 1 && n1 < N)
    ((float4*)agg)[(size_t)n1 * 16 + c4] = make_float4(b0, b1, b2, b3);
}

// ---------------- mlpA (MFMA): z1 = ((1+eps)h + agg)@W1 + b1, bf16 out + stats ----------------
__global__ __launch_bounds__(256) void k_mlpA(
    const ushort* __restrict__ h2, const float* __restrict__ agg,
    const ushort* __restrict__ wfrag, const float* __restrict__ bvec,
    const float* __restrict__ epsl, ushort* __restrict__ z1b,
    float* __restrict__ stats, int NT, int nwaves)
{
  __shared__ float sred[128];
  __shared__ ushort ldsT[4][16][72];
  if (threadIdx.x < 128) sred[threadIdx.x] = 0.f;
  __syncthreads();
  int lane = threadIdx.x & 63;
  int wid = threadIdx.x >> 6;
  int gwave = blockIdx.x * 4 + wid;
  int hi = lane >> 4, lo = lane & 15;
  float epsv = 1.f + epsl[0];
  bhalf8 af[8];
  #pragma unroll
  for (int f = 0; f < 8; ++f)
    af[f] = *(const bhalf8*)(wfrag + f * 512 + lane * 8);
  float4 bq[4];
  #pragma unroll
  for (int jt = 0; jt < 4; ++jt)
    bq[jt] = *(const float4*)(bvec + jt * 16 + hi * 4);
  float sS[4][4] = {{0}}, sQ[4][4] = {{0}};
  for (int mt = gwave; mt < NT; mt += nwaves) {
    int node = mt * 16 + lo;
    const ushort* hrow = h2 + (size_t)node * DD;
    const float* arow = agg + (size_t)node * DD;
    bhalf8 bfr[2];
    #pragma unroll
    for (int kb = 0; kb < 2; ++kb) {
      int k0 = kb * 32 + hi * 8;
      uint4 hv = *(const uint4*)(hrow + k0);
      float4 aa = *(const float4*)(arow + k0);
      float4 ab = *(const float4*)(arow + k0 + 4);
      float xr[8];
      xr[0] = fmaf(epsv, __uint_as_float(hv.x << 16), aa.x);
      xr[1] = fmaf(epsv, __uint_as_float(hv.x & 0xFFFF0000u), aa.y);
      xr[2] = fmaf(epsv, __uint_as_float(hv.y << 16), aa.z);
      xr[3] = fmaf(epsv, __uint_as_float(hv.y & 0xFFFF0000u), aa.w);
      xr[4] = fmaf(epsv, __uint_as_float(hv.z << 16), ab.x);
      xr[5] = fmaf(epsv, __uint_as_float(hv.z & 0xFFFF0000u), ab.y);
      xr[6] = fmaf(epsv, __uint_as_float(hv.w << 16), ab.z);
      xr[7] = fmaf(epsv, __uint_as_float(hv.w & 0xFFFF0000u), ab.w);
      bhalf8 b8;
      #pragma unroll
      for (int r = 0; r < 8; ++r) b8[r] = (short)f2bf(xr[r]);
      bfr[kb] = b8;
    }
    fx4 acc[4];
    #pragma unroll
    for (int jt = 0; jt < 4; ++jt) {
      fx4 a = {0.f, 0.f, 0.f, 0.f};
      a = __builtin_amdgcn_mfma_f32_16x16x32_bf16(af[jt * 2 + 0], bfr[0], a, 0, 0, 0);
      a = __builtin_amdgcn_mfma_f32_16x16x32_bf16(af[jt * 2 + 1], bfr[1], a, 0, 0, 0);
      acc[jt] = a;
    }
    #pragma unroll
    for (int jt = 0; jt < 4; ++jt) {
      float z0 = acc[jt][0] + bq[jt].x;
      float z1 = acc[jt][1] + bq[jt].y;
      float z2 = acc[jt][2] + bq[jt].z;
      float z3 = acc[jt][3] + bq[jt].w;
      sS[jt][0] += z0; sQ[jt][0] += z0 * z0;
      sS[jt][1] += z1; sQ[jt][1] += z1 * z1;
      sS[jt][2] += z2; sQ[jt][2] += z2 * z2;
      sS[jt][3] += z3; sQ[jt][3] += z3 * z3;
      uint p0 = ((uint)f2bf(z1) << 16) | f2bf(z0);
      uint p1 = ((uint)f2bf(z3) << 16) | f2bf(z2);
      int jphys = jt ^ (lo & 3);
      *(uint2*)&ldsT[wid][lo][jphys * 16 + hi * 4] = make_uint2(p0, p1);
    }
    int row = lane >> 2, pch = lane & 3;
    int pphys = pch ^ (row & 3);
    const uint4* src = (const uint4*)&ldsT[wid][row][pphys * 16];
    uint4 v0 = src[0], v1 = src[1];
    uint4* dst = (uint4*)(z1b + ((size_t)(mt * 16 + row)) * DD + pch * 16);
    dst[0] = v0; dst[1] = v1;
  }
  #pragma unroll
  for (int o = 1; o < 16; o <<= 1)
    #pragma unroll
    for (int jt = 0; jt < 4; ++jt)
      #pragma unroll
      for (int q = 0; q < 4; ++q) {
        sS[jt][q] += __shfl_xor(sS[jt][q], o);
        sQ[jt][q] += __shfl_xor(sQ[jt][q], o);
      }
  if (lo == 0) {
    #pragma unroll
    for (int jt = 0; jt < 4; ++jt)
      #pragma unroll
      for (int q = 0; q < 4; ++q) {
        atomicAdd(&sred[jt * 16 + hi * 4 + q], sS[jt][q]);
        atomicAdd(&sred[64 + jt * 16 + hi * 4 + q], sQ[jt][q]);
      }
  }
  __syncthreads();
  if (threadIdx.x < 128) atomicAdd(&stats[threadIdx.x], sred[threadIdx.x]);
}

// ---------------- mlpB (MFMA): z2 = relu(BN1(z1))@W2 + b2, bf16 in-place + stats2 ----------------
__global__ __launch_bounds__(256) void k_mlpB(
    ushort* __restrict__ z1b, const ushort* __restrict__ wfrag,
    const float* __restrict__ bvec, const float* __restrict__ g1,
    const float* __restrict__ b1g, const float* __restrict__ statsIn,
    float* __restrict__ statsOut, float invN, int NT, int nwaves)
{
  __shared__ float sred[128];
  __shared__ float scl[DD], shl[DD];
  __shared__ ushort ldsT[4][16][72];
  if (threadIdx.x < 128) sred[threadIdx.x] = 0.f;
  if (threadIdx.x < DD) {
    int j = threadIdx.x;
    float m = statsIn[j] * invN;
    float v = statsIn[DD + j] * invN - m * m;
    float sc = rsqrtf(v + BNEPS) * g1[j];
    scl[j] = sc;
    shl[j] = b1g[j] - m * sc;
  }
  __syncthreads();
  int lane = threadIdx.x & 63;
  int wid = threadIdx.x >> 6;
  int gwave = blockIdx.x * 4 + wid;
  int hi = lane >> 4, lo = lane & 15;
  bhalf8 af[8];
  #pragma unroll
  for (int f = 0; f < 8; ++f)
    af[f] = *(const bhalf8*)(wfrag + f * 512 + lane * 8);
  float4 bq[4];
  #pragma unroll
  for (int jt = 0; jt < 4; ++jt)
    bq[jt] = *(const float4*)(bvec + jt * 16 + hi * 4);
  float4 scr[2][2], shr[2][2];
  #pragma unroll
  for (int kb = 0; kb < 2; ++kb) {
    int k0 = kb * 32 + hi * 8;
    scr[kb][0] = *(const float4*)&scl[k0];
    scr[kb][1] = *(const float4*)&scl[k0 + 4];
    shr[kb][0] = *(const float4*)&shl[k0];
    shr[kb][1] = *(const float4*)&shl[k0 + 4];
  }
  float sS[4][4] = {{0}}, sQ[4][4] = {{0}};
  for (int mt = gwave; mt < NT; mt += nwaves) {
    int node = mt * 16 + lo;
    const ushort* zrow = z1b + (size_t)node * DD;
    bhalf8 bfr[2];
    #pragma unroll
    for (int kb = 0; kb < 2; ++kb) {
      int k0 = kb * 32 + hi * 8;
      uint4 zv = *(const uint4*)(zrow + k0);
      float xr[8];
      xr[0] = __uint_as_float(zv.x << 16);
      xr[1] = __uint_as_float(zv.x & 0xFFFF0000u);
      xr[2] = __uint_as_float(zv.y << 16);
      xr[3] = __uint_as_float(zv.y & 0xFFFF0000u);
      xr[4] = __uint_as_float(zv.z << 16);
      xr[5] = __uint_as_float(zv.z & 0xFFFF0000u);
      xr[6] = __uint_as_float(zv.w << 16);
      xr[7] = __uint_as_float(zv.w & 0xFFFF0000u);
      xr[0] = fmaxf(fmaf(xr[0], scr[kb][0].x, shr[kb][0].x), 0.f);
      xr[1] = fmaxf(fmaf(xr[1], scr[kb][0].y, shr[kb][0].y), 0.f);
      xr[2] = fmaxf(fmaf(xr[2], scr[kb][0].z, shr[kb][0].z), 0.f);
      xr[3] = fmaxf(fmaf(xr[3], scr[kb][0].w, shr[kb][0].w), 0.f);
      xr[4] = fmaxf(fmaf(xr[4], scr[kb][1].x, shr[kb][1].x), 0.f);
      xr[5] = fmaxf(fmaf(xr[5], scr[kb][1].y, shr[kb][1].y), 0.f);
      xr[6] = fmaxf(fmaf(xr[6], scr[kb][1].z, shr[kb][1].z), 0.f);
      xr[7] = fmaxf(fmaf(xr[7], scr[kb][1].w, shr[kb][1].w), 0.f);
      bhalf8 b8;
      #pragma unroll
      for (int r = 0; r < 8; ++r) b8[r] = (short)f2bf(xr[r]);
      bfr[kb] = b8;
    }
    fx4 acc[4];
    #pragma unroll
    for (int jt = 0; jt < 4; ++jt) {
      fx4 a = {0.f, 0.f, 0.f, 0.f};
      a = __builtin_amdgcn_mfma_f32_16x16x32_bf16(af[jt * 2 + 0], bfr[0], a, 0, 0, 0);
      a = __builtin_amdgcn_mfma_f32_16x16x32_bf16(af[jt * 2 + 1], bfr[1], a, 0, 0, 0);
      acc[jt] = a;
    }
    #pragma unroll
    for (int jt = 0; jt < 4; ++jt) {
      float z0 = acc[jt][0] + bq[jt].x;
      float z1 = acc[jt][1] + bq[jt].y;
      float z2 = acc[jt][2] + bq[jt].z;
      float z3 = acc[jt][3] + bq[jt].w;
      sS[jt][0] += z0; sQ[jt][0] += z0 * z0;
      sS[jt][1] += z1; sQ[jt][1] += z1 * z1;
      sS[jt][2] += z2; sQ[jt][2] += z2 * z2;
      sS[jt][3] += z3; sQ[jt][3] += z3 * z3;
      uint p0 = ((uint)f2bf(z1) << 16) | f2bf(z0);
      uint p1 = ((uint)f2bf(z3) << 16) | f2bf(z2);
      int jphys = jt ^ (lo & 3);
      *(uint2*)&ldsT[wid][lo][jphys * 16 + hi * 4] = make_uint2(p0, p1);
    }
    int row = lane >> 2, pch = lane & 3;
    int pphys = pch ^ (row & 3);
    const uint4* src = (const uint4*)&ldsT[wid][row][pphys * 16];
    uint4 v0 = src[0], v1 = src[1];
    uint4* dst = (uint4*)(z1b + ((size_t)(mt * 16 + row)) * DD + pch * 16);
    dst[0] = v0; dst[1] = v1;
  }
  #pragma unroll
  for (int o = 1; o < 16; o <<= 1)
    #pragma unroll
    for (int jt = 0; jt < 4; ++jt)
      #pragma unroll
      for (int q = 0; q < 4; ++q) {
        sS[jt][q] += __shfl_xor(sS[jt][q], o);
        sQ[jt][q] += __shfl_xor(sQ[jt][q], o);
      }
  if (lo == 0) {
    #pragma unroll
    for (int jt = 0; jt < 4; ++jt)
      #pragma unroll
      for (int q = 0; q < 4; ++q) {
        atomicAdd(&sred[jt * 16 + hi * 4 + q], sS[jt][q]);
        atomicAdd(&sred[64 + jt * 16 + hi * 4 + q], sQ[jt][q]);
      }
  }
  __syncthreads();
  if (threadIdx.x < 128) atomicAdd(&statsOut[threadIdx.x], sred[threadIdx.x]);
}

// ---------------- bnout + fingerprint: block per graph, bf16 in ----------------
__global__ __launch_bounds__(256) void k_bnout_fp(
    const ushort* __restrict__ zb, ushort* __restrict__ h2,
    const float* __restrict__ g2, const float* __restrict__ b2g,
    const float* __restrict__ statsIn, const int* __restrict__ gs,
    float* __restrict__ fp, float* __restrict__ outp,
    int l, float invN)
{
  __shared__ float sc[DD], sh[DD], part[4 * DD];
  int tid = threadIdx.x;
  if (tid < DD) {
    float m = statsIn[tid] * invN;
    float v = statsIn[DD + tid] * invN - m * m;
    float inv = rsqrtf(v + BNEPS);
    float scale = inv * g2[tid];
    sc[tid] = scale;
    sh[tid] = b2g[tid] - m * scale;
  }
  __syncthreads();
  int g = blockIdx.x;
  int r0 = gs[g], r1 = gs[g + 1];
  int ch = tid & 63, rg = tid >> 6;
  bool last = (l == LL - 1);
  float facc = 0.f;
  for (int r = r0 + rg; r < r1; r += 4) {
    float z = bf2f(zb[(size_t)r * DD + ch]);
    float y = z * sc[ch] + sh[ch];
    if (!last) y = fmaxf(y, 0.f);
    h2[(size_t)r * DD + ch] = f2bf(y);
    if (last) outp[(size_t)r * DD + ch] = y;
    facc += y;
  }
  part[rg * DD + ch] = facc;
  __syncthreads();
  if (tid < DD) {
    float s = part[tid] + part[DD + tid] + part[2 * DD + tid] + part[3 * DD + tid];
    fp[((size_t)g * LL + l) * DD + tid] = s;
  }
}

extern "C" void kernel_launch(void* const* d_in, const int* in_sizes, int n_in,
                              void* d_out, int out_size, void* d_ws, size_t ws_size,
                              hipStream_t stream)
{
  const int*   x_feats    = (const int*)d_in[0];
  const int*   edge_index = (const int*)d_in[1];
  const int*   edge_attr  = (const int*)d_in[2];
  const int*   batch      = (const int*)d_in[3];
  const float* atom_emb   = (const float*)d_in[4];
  const float* bond_emb   = (const float*)d_in[5];
  const float* eps        = (const float*)d_in[6];
  const float* W1         = (const float*)d_in[7];
  const float* b1         = (const float*)d_in[8];
  const float* bn1_g      = (const float*)d_in[9];
  const float* bn1_b      = (const float*)d_in[10];
  const float* W2         = (const float*)d_in[11];
  const float* b2         = (const float*)d_in[12];
  const float* bn_g       = (const float*)d_in[13];
  const float* bn_b       = (const float*)d_in[14];

  int N = in_sizes[3];
  int E = in_sizes[1] / 2;
  int NB = (N + SCB - 1) / SCB;
  int NT = N >> 4;
  float invN = 1.f / (float)N;

  float* out = (float*)d_out;
  float* fp  = out + (size_t)N * DD;

  float* buf     = (float*)d_ws;                 // N*D fp32 (agg)
  float* stats   = buf + (size_t)N * DD;         // L*256
  float* bcomb   = stats + LL * 256;             // L*216*D
  ushort* h2     = (ushort*)(bcomb + LL * 216 * DD); // N*D bf16
  ushort* z1b    = h2 + (size_t)N * DD;          // N*D bf16 (z1 -> z2)
  ushort* wfrag  = z1b + (size_t)N * DD;         // L*2*4096
  int* deg8      = (int*)(wfrag + LL * 2 * 4096);// NCPY*N
  int* rank      = deg8 + NCPY * (size_t)N;      // E
  int* scanned   = rank + E;                     // N
  int* bsum      = scanned + N;                  // 128
  int* boff      = bsum + 128;                   // 128
  int* gs        = boff + 128;                   // G+1
  int* rcarr     = gs + (GG + 1);                // E

  hipMemsetAsync(stats, 0, LL * 256 * sizeof(float), stream);
  hipMemsetAsync(deg8, 0, NCPY * (size_t)N * sizeof(int), stream);

  k_atom<<<(N * 16 + 255) / 256, 256, 0, stream>>>(x_feats, atom_emb, h2, N);
  k_hist<<<(E + 255) / 256, 256, 0, stream>>>(edge_index, deg8, rank, E, N);
  k_scan1<<<NB, SCB, 0, stream>>>(deg8, scanned, bsum, N);
  k_scan2<<<1, 128, 0, stream>>>(bsum, boff, NB);
  k_fill<<<(E + 255) / 256, 256, 0, stream>>>(edge_index, edge_attr, scanned,
                                              boff, rank, deg8, rcarr, E, N);
  k_bcomb<<<(LL * 216 * DD + 255) / 256, 256, 0, stream>>>(bond_emb, bcomb);
  k_bounds<<<(GG + 256) / 256, 256, 0, stream>>>(batch, gs, N);
  k_wprep<<<(LL * 2 * 4096 + 255) / 256, 256, 0, stream>>>(W1, W2, wfrag);

  const int gridM = 640;
  const int nwaves = gridM * 4;
  const int gridG = (N + 7) / 8;        // 4 waves/block × 2 nodes/wave
  for (int l = 0; l < LL; ++l) {
    float* s1 = stats + l * 256;
    float* s2 = s1 + 128;
    k_gather<<<gridG, 256, 0, stream>>>(h2, rcarr, scanned, boff,
                                        bcomb + (size_t)l * 216 * DD, buf, N, E);
    k_mlpA<<<gridM, 256, 0, stream>>>(h2, buf, wfrag + (size_t)(l * 2 + 0) * 4096,
                                      b1 + l * DD, eps + l, z1b, s1, NT, nwaves);
    k_mlpB<<<gridM, 256, 0, stream>>>(z1b, wfrag + (size_t)(l * 2 + 1) * 4096,
                                      b2 + l * DD, bn1_g + l * DD, bn1_b + l * DD,
                                      s1, s2, invN, NT, nwaves);
    k_bnout_fp<<<GG, 256, 0, stream>>>(z1b, h2, bn_g + l * DD, bn_b + l * DD,
                                       s2, gs, fp, out, l, invN);
  }
}